// Round 10
// baseline (372.595 us; speedup 1.0000x reference)
//
#include <hip/hip_runtime.h>

// Problem constants
#define KCB   1024      // codebook size
#define DCV   64        // code dim
#define HWN   4096      // H*W
#define CHW   262144    // DCV*HWN per batch
#define NTOT  131072    // 32*HWN

// Output offsets (floats), concatenated in reference return order
#define O_ZQ   0
#define O_IDX  8388608
#define O_LOSS 8519680
#define O_NE   8519681
#define O_NCS  8585217
#define O_NEA  8586241

// Workspace byte offsets — TOTAL 790,784 B < 1 MiB (hard limit: round-3 ws
// overflow corrupted the harness's pristine input copy).
#define W_LOSS  0                 // 8 B   double
#define W_CTR   64                // 4 B   int
#define W_E2    256               // 4 KB
#define W_HLT   4352              // 256 KB chunk-major fp16 hi/lo codebook
                                  //   [ch(16)][arr(2)][q(8)][code(64)][8] halfs
#define W_EMBT  266496            // 256 KB transposed codebook [d][code] f32
#define W_RLIST 528640            // 256 KB refine list (cap 65536)
// end = 790784

#define RCAP   65536
// fp16 hi + (lo*2048) split: worst-case pairwise dist error ~3e-4.
// 1e-3 = >3x margin.
#define MARGIN 1e-3f

typedef __attribute__((ext_vector_type(8))) _Float16 half8v;
typedef __attribute__((ext_vector_type(4))) float f32x4;

// ---------------------------------------------------------------------------
// K0: init NEA=0.99*ea, NCS=0.99*cs; e2=||e||^2 (fp64 accum); chunk-major
// fp16 hi/lo codebook hl (lo scaled x2048); transposed f32 codebook
// embT[d][code]; zero scalars.
// ---------------------------------------------------------------------------
__global__ __launch_bounds__(256) void k_init(
    const float* __restrict__ emb, const float* __restrict__ ea,
    const float* __restrict__ cs, float* __restrict__ out,
    float* __restrict__ e2, _Float16* __restrict__ hl,
    float* __restrict__ embT, double* __restrict__ loss, int* __restrict__ ctr)
{
    int j = blockIdx.x * 256 + threadIdx.x;   // 0..65535
    out[O_NEA + j] = 0.99f * ea[j];

    // embT[d*1024+code] = emb[code*64+d]; j = code*64+d -> coalesced read
    {
        int code = j >> 6, d = j & 63;
        embT[d * KCB + code] = emb[j];
    }
    if (j < KCB) {
        out[O_NCS + j] = 0.99f * cs[j];
        const float* er = emb + j * DCV;
        double s = 0.0;
        #pragma unroll
        for (int d = 0; d < DCV; ++d) { double v = (double)er[d]; s += v * v; }
        e2[j] = (float)s;
    }
    if (j < 8192) {
        int code = j >> 3, q = j & 7;
        int ch = code >> 6, lc = code & 63;
        const float* src = emb + code * DCV + q * 8;
        half8v h, l;
        #pragma unroll
        for (int t = 0; t < 8; ++t) {
            float x = src[t];
            _Float16 hx = (_Float16)x;
            h[t] = hx;
            l[t] = (_Float16)((x - (float)hx) * 2048.0f);
        }
        *(half8v*)(hl + (size_t)(((ch * 2 + 0) * 8 + q) * 64 + lc) * 8) = h;
        *(half8v*)(hl + (size_t)(((ch * 2 + 1) * 8 + q) * 64 + lc) * 8) = l;
    }
    if (j == 0) { *loss = 0.0; *ctr = 0; }
}

// ---------------------------------------------------------------------------
// K1: MFMA distance argmin, fp16 hi/lo, double-buffered async LDS staging.
// Block = 128 rows (4 waves x 32). 16 chunks of 64 codes staged via
// global_load_lds(16B). Per 16-code sub: 12 mfma_f32_16x16x32_f16 in 4
// independent chains. dist-x^2 = e2 - 2*(ah + ac/2048). Near-ties
// (gap < MARGIN) flagged for fp64 refine.
// ---------------------------------------------------------------------------
__global__ __launch_bounds__(256, 2) void k_dist(
    const float* __restrict__ ze, const char* __restrict__ hl,
    const float* __restrict__ e2g, float* __restrict__ out,
    int* __restrict__ ctr, int* __restrict__ rlist)
{
    __shared__ _Float16 lds[2][8192];     // 2 x 16 KB: [arr(2)][q(8)][code(64)][8]

    int tid  = threadIdx.x;
    int lane = tid & 63, w = tid >> 6;
    int g = lane >> 4, c = lane & 15;

    #define STAGE(buf, ch)                                                     \
        {                                                                      \
            _Pragma("unroll")                                                  \
            for (int r = 0; r < 4; ++r) {                                      \
                int off = (r * 4 + w) * 1024 + lane * 16;                      \
                __builtin_amdgcn_global_load_lds(                              \
                    (const __attribute__((address_space(1))) void*)            \
                        (hl + (size_t)(ch) * 16384 + off),                     \
                    (__attribute__((address_space(3))) void*)                  \
                        ((char*)lds[buf] + off),                               \
                    16, 0, 0);                                                 \
            }                                                                  \
        }

    // A-fragments: row = lane&15, k = kh*32 + 8*(lane>>4) + j (same bijection as B)
    int rowbase = blockIdx.x * 128 + w * 32;
    half8v ahi[2][2], alo[2][2];
    #pragma unroll
    for (int t = 0; t < 2; ++t) {
        int n = rowbase + t * 16 + c;
        const float* base = ze + (size_t)(n >> 12) * CHW + (n & 4095);
        #pragma unroll
        for (int kh = 0; kh < 2; ++kh) {
            #pragma unroll
            for (int j = 0; j < 8; ++j) {
                int k = kh * 32 + g * 8 + j;
                float x = base[(size_t)k * HWN];
                _Float16 hx = (_Float16)x;
                ahi[t][kh][j] = hx;
                alo[t][kh][j] = (_Float16)((x - (float)hx) * 2048.0f);
            }
        }
    }

    float best[8], second[8];
    int   bidx[8];
    #pragma unroll
    for (int i = 0; i < 8; ++i) { best[i] = 3.4e38f; second[i] = 3.4e38f; bidx[i] = 0; }

    STAGE(0, 0);
    __syncthreads();          // drains vmcnt -> buf0 ready

    int cur = 0;
    for (int ch = 0; ch < 16; ++ch) {
        if (ch < 15) STAGE(cur ^ 1, ch + 1);   // async prefetch next chunk

        const _Float16* L = lds[cur];
        #pragma unroll
        for (int sub = 0; sub < 4; ++sub) {
            int boff = (sub * 16 + c) * 8;
            half8v bh0 = *(const half8v*)&L[(g * 64) * 8 + boff];
            half8v bh1 = *(const half8v*)&L[((4 + g) * 64) * 8 + boff];
            half8v bl0 = *(const half8v*)&L[((8 + g) * 64) * 8 + boff];
            half8v bl1 = *(const half8v*)&L[((12 + g) * 64) * 8 + boff];

            f32x4 a0h = {0.f, 0.f, 0.f, 0.f}, a1h = {0.f, 0.f, 0.f, 0.f};
            f32x4 a0c = {0.f, 0.f, 0.f, 0.f}, a1c = {0.f, 0.f, 0.f, 0.f};
            a0h = __builtin_amdgcn_mfma_f32_16x16x32_f16(ahi[0][0], bh0, a0h, 0, 0, 0);
            a1h = __builtin_amdgcn_mfma_f32_16x16x32_f16(ahi[1][0], bh0, a1h, 0, 0, 0);
            a0h = __builtin_amdgcn_mfma_f32_16x16x32_f16(ahi[0][1], bh1, a0h, 0, 0, 0);
            a1h = __builtin_amdgcn_mfma_f32_16x16x32_f16(ahi[1][1], bh1, a1h, 0, 0, 0);
            a0c = __builtin_amdgcn_mfma_f32_16x16x32_f16(ahi[0][0], bl0, a0c, 0, 0, 0);
            a1c = __builtin_amdgcn_mfma_f32_16x16x32_f16(ahi[1][0], bl0, a1c, 0, 0, 0);
            a0c = __builtin_amdgcn_mfma_f32_16x16x32_f16(ahi[0][1], bl1, a0c, 0, 0, 0);
            a1c = __builtin_amdgcn_mfma_f32_16x16x32_f16(ahi[1][1], bl1, a1c, 0, 0, 0);
            a0c = __builtin_amdgcn_mfma_f32_16x16x32_f16(alo[0][0], bh0, a0c, 0, 0, 0);
            a1c = __builtin_amdgcn_mfma_f32_16x16x32_f16(alo[1][0], bh0, a1c, 0, 0, 0);
            a0c = __builtin_amdgcn_mfma_f32_16x16x32_f16(alo[0][1], bh1, a0c, 0, 0, 0);
            a1c = __builtin_amdgcn_mfma_f32_16x16x32_f16(alo[1][1], bh1, a1c, 0, 0, 0);

            float e2v = e2g[ch * 64 + sub * 16 + c];   // 4KB table, L1-resident
            int  code = ch * 64 + sub * 16 + c;
            #pragma unroll
            for (int t = 0; t < 2; ++t) {
                f32x4 avh = t ? a1h : a0h;
                f32x4 avc = t ? a1c : a0c;
                #pragma unroll
                for (int r = 0; r < 4; ++r) {
                    int i = t * 4 + r;
                    float dotv = fmaf(avc[r], 4.8828125e-4f, avh[r]);  // ah + ac/2048
                    float s = fmaf(-2.f, dotv, e2v);    // dist - x^2 (row-const drop)
                    bool lb = s < best[i];
                    second[i] = fminf(second[i], fmaxf(best[i], s));
                    best[i]   = fminf(best[i], s);
                    bidx[i]   = lb ? code : bidx[i];
                }
            }
        }
        __syncthreads();      // next buffer ready; current safe to overwrite
        cur ^= 1;
    }

    #pragma unroll
    for (int i = 0; i < 8; ++i) {
        float b = best[i], s2 = second[i];
        int bi = bidx[i];
        #pragma unroll
        for (int m = 1; m < 16; m <<= 1) {
            float ob = __shfl_xor(b, m, 64);
            float os = __shfl_xor(s2, m, 64);
            int   oi = __shfl_xor(bi, m, 64);
            float ns = fminf(fmaxf(b, ob), fminf(s2, os));
            bi = (ob < b || (ob == b && oi < bi)) ? oi : bi;
            b  = fminf(b, ob);
            s2 = ns;
        }
        if (c == 0) {
            int t = i >> 2, r = i & 3;
            int n = rowbase + t * 16 + g * 4 + r;
            out[O_IDX + n] = (float)bi;
            if (s2 - b < MARGIN) {
                int p = atomicAdd(ctr, 1);
                if (p < RCAP) rlist[p] = n;
            }
        }
    }
    #undef STAGE
}

// ---------------------------------------------------------------------------
// K2: fp64 exact argmin for flagged near-ties; fixes index only. One wave
// per candidate.
// ---------------------------------------------------------------------------
__global__ __launch_bounds__(256) void k_refine(
    const float* __restrict__ ze, const float* __restrict__ emb,
    float* __restrict__ out, const int* __restrict__ ctr,
    const int* __restrict__ rlist)
{
    int lane = threadIdx.x & 63;
    int gw   = (blockIdx.x * blockDim.x + threadIdx.x) >> 6;
    int nw   = (gridDim.x * blockDim.x) >> 6;
    int cnt  = *ctr;
    if (cnt > RCAP) cnt = RCAP;

    for (int i = gw; i < cnt; i += nw) {
        int n = rlist[i];
        const float* zp = ze + (size_t)(n >> 12) * CHW + (n & 4095);
        float x[DCV];
        #pragma unroll
        for (int d = 0; d < DCV; ++d) x[d] = zp[(size_t)d * HWN];  // uniform -> broadcast

        double bd = 1e300;
        int    bi = 0;
        #pragma unroll 1
        for (int cc = 0; cc < KCB / 64; ++cc) {
            int k = cc * 64 + lane;
            const float4* eb4 = (const float4*)(emb + k * DCV);
            double a0 = 0.0, a1 = 0.0;
            #pragma unroll
            for (int q = 0; q < DCV / 4; ++q) {
                float4 v = eb4[q];
                double d0 = (double)x[q * 4 + 0] - (double)v.x;
                double d1 = (double)x[q * 4 + 1] - (double)v.y;
                double d2 = (double)x[q * 4 + 2] - (double)v.z;
                double d3 = (double)x[q * 4 + 3] - (double)v.w;
                a0 = fma(d0, d0, a0); a1 = fma(d1, d1, a1);
                a0 = fma(d2, d2, a0); a1 = fma(d3, d3, a1);
            }
            double dist = a0 + a1;
            if (dist < bd || (dist == bd && k < bi)) { bd = dist; bi = k; }
        }
        #pragma unroll
        for (int off = 32; off > 0; off >>= 1) {
            double od = __shfl_xor(bd, off, 64);
            int    oi = __shfl_xor(bi, off, 64);
            if (od < bd || (od == bd && oi < bi)) { bd = od; bi = oi; }
        }
        if (lane == 0) out[O_IDX + n] = (float)bi;
    }
}

// ---------------------------------------------------------------------------
// K3a: z_q_st + commitment loss, pure streaming at full occupancy.
// Thread <-> (b, d, hw4): float4 read/write, embT row gather (L1, wave-
// uniform d). Grid 8192 blocks. ~67 MB total -> HBM-roofline shaped.
// ---------------------------------------------------------------------------
__global__ __launch_bounds__(256) void k_zq(
    const float* __restrict__ ze, const float* __restrict__ embT,
    float* __restrict__ out, double* __restrict__ loss)
{
    int j  = blockIdx.x * 256 + threadIdx.x;  // 0..2M-1
    int b  = j >> 16;          // 32
    int d  = (j >> 10) & 63;   // 64
    int h4 = j & 1023;         // float4 unit over hw

    size_t off = (size_t)b * CHW + (size_t)d * HWN + h4 * 4;
    float4 zv = *(const float4*)(ze + off);
    float4 iv = *(const float4*)(out + O_IDX + b * HWN + h4 * 4);
    const float* eT = embT + d * KCB;
    float e0 = eT[(int)iv.x], e1 = eT[(int)iv.y];
    float e2 = eT[(int)iv.z], e3 = eT[(int)iv.w];

    float4 q;
    q.x = zv.x + (e0 - zv.x);   // straight-through f32 rounding
    q.y = zv.y + (e1 - zv.y);
    q.z = zv.z + (e2 - zv.z);
    q.w = zv.w + (e3 - zv.w);
    *(float4*)(out + O_ZQ + off) = q;

    float d0 = zv.x - e0, d1 = zv.y - e1, d2 = zv.z - e2, d3 = zv.w - e3;
    float lp = fmaf(d0, d0, fmaf(d1, d1, fmaf(d2, d2, d3 * d3)));

    #pragma unroll
    for (int o = 32; o > 0; o >>= 1) lp += __shfl_down(lp, o, 64);
    __shared__ float wsum[4];
    int lane = threadIdx.x & 63, wid = threadIdx.x >> 6;
    if (lane == 0) wsum[wid] = lp;
    __syncthreads();
    if (threadIdx.x == 0) {
        double s = (double)wsum[0] + wsum[1] + wsum[2] + wsum[3];
        atomicAdd(loss, s);
    }
}

// ---------------------------------------------------------------------------
// K3b: dw segment-sum + counts. Block = (dim d, chunk of 4 batches):
// 512 blocks (2/CU, 8 waves/CU), LDS 8 KB. All global reads coalesced;
// ds_atomic bank = idx%32 (~2-way). d==0 blocks also bin counts.
// Flush: 0.01*bins into NEA (atomic across the 8 chunk-blocks per (k,d)).
// ---------------------------------------------------------------------------
__global__ __launch_bounds__(256) void k_dw(
    const float* __restrict__ ze, const float* __restrict__ outIdx,
    float* __restrict__ out)
{
    int d = blockIdx.x & 63, chunk = blockIdx.x >> 6;   // 8 chunks x 4 batches
    __shared__ float bins[KCB];
    __shared__ float cnt[KCB];
    for (int i = threadIdx.x; i < KCB; i += 256) { bins[i] = 0.f; cnt[i] = 0.f; }
    __syncthreads();

    #pragma unroll
    for (int bb = 0; bb < 4; ++bb) {
        int b = chunk * 4 + bb;
        const float* zp = ze + (size_t)b * CHW + (size_t)d * HWN;
        const float* ip = outIdx + b * HWN;
        for (int t = threadIdx.x; t < HWN; t += 256) {
            int idx = (int)ip[t];
            atomicAdd(&bins[idx], zp[t]);
            if (d == 0) atomicAdd(&cnt[idx], 1.f);
        }
    }
    __syncthreads();

    for (int k = threadIdx.x; k < KCB; k += 256) {
        float v = bins[k];
        if (v != 0.f) atomicAdd(&out[O_NEA + k * DCV + d], 0.01f * v);
        if (d == 0) {
            float cv = cnt[k];
            if (cv != 0.f) atomicAdd(&out[O_NCS + k], 0.01f * cv);
        }
    }
}

// ---------------------------------------------------------------------------
// K4: fused stats+embed: each block redundantly reduces NCS (4 KB) to n,
// then computes its 256 NE outputs. Block 0 also writes the loss scalar.
// ---------------------------------------------------------------------------
__global__ __launch_bounds__(256) void k_fin(
    float* __restrict__ out, const double* __restrict__ loss)
{
    __shared__ float red[4];
    int t = threadIdx.x;
    float s = 0.f;
    #pragma unroll
    for (int q = 0; q < 4; ++q) s += out[O_NCS + t * 4 + q];
    #pragma unroll
    for (int off = 32; off > 0; off >>= 1) s += __shfl_down(s, off, 64);
    int lane = t & 63, wid = t >> 6;
    if (lane == 0) red[wid] = s;
    __syncthreads();
    float n = red[0] + red[1] + red[2] + red[3];

    int j = blockIdx.x * 256 + t;      // 0..65535
    int k = j >> 6;
    float ncs = out[O_NCS + k];
    float sm = (ncs + 1e-5f) / (n + (float)KCB * 1e-5f) * n;
    out[O_NE + j] = out[O_NEA + j] / sm;

    if (blockIdx.x == 0 && t == 0)
        out[O_LOSS] = (float)(0.25 * (*loss) / (double)(NTOT * DCV));
}

// ---------------------------------------------------------------------------
extern "C" void kernel_launch(void* const* d_in, const int* in_sizes, int n_in,
                              void* d_out, int out_size, void* d_ws, size_t ws_size,
                              hipStream_t stream)
{
    const float* ze  = (const float*)d_in[0];
    const float* emb = (const float*)d_in[1];
    const float* cs  = (const float*)d_in[2];
    const float* ea  = (const float*)d_in[3];
    float* out = (float*)d_out;

    char*     w     = (char*)d_ws;
    double*   loss  = (double*)(w + W_LOSS);
    int*      ctr   = (int*)(w + W_CTR);
    float*    e2    = (float*)(w + W_E2);
    _Float16* hl    = (_Float16*)(w + W_HLT);
    float*    embT  = (float*)(w + W_EMBT);
    int*      rlist = (int*)(w + W_RLIST);

    k_init  <<<256, 256, 0, stream>>>(emb, ea, cs, out, e2, hl, embT, loss, ctr);
    k_dist  <<<1024, 256, 0, stream>>>(ze, (const char*)hl, e2, out, ctr, rlist);
    k_refine<<<256, 256, 0, stream>>>(ze, emb, out, ctr, rlist);
    k_zq    <<<8192, 256, 0, stream>>>(ze, embT, out, loss);
    k_dw    <<<512, 256, 0, stream>>>(ze, (const float*)(out + O_IDX), out);
    k_fin   <<<256, 256, 0, stream>>>(out, loss);
}

// Round 11
// 289.685 us; speedup vs baseline: 1.2862x; 1.2862x over previous
//
#include <hip/hip_runtime.h>

// Problem constants
#define KCB   1024      // codebook size
#define DCV   64        // code dim
#define HWN   4096      // H*W
#define CHW   262144    // DCV*HWN per batch
#define NTOT  131072    // 32*HWN

// Output offsets (floats), concatenated in reference return order
#define O_ZQ   0
#define O_IDX  8388608
#define O_LOSS 8519680
#define O_NE   8519681
#define O_NCS  8585217
#define O_NEA  8586241

// Workspace byte offsets — TOTAL 823,552 B < 1 MiB (hard limit: round-3 ws
// overflow corrupted the harness's pristine input copy).
#define W_CTR   64                // 4 B   int
#define W_E2    256               // 4 KB
#define W_HLT   4352              // 256 KB chunk-major fp16 hi/lo codebook
                                  //   [ch(16)][arr(2)][q(8)][code(64)][8] halfs
#define W_EMBT  266496            // 256 KB transposed codebook [d][code] f32
#define W_RLIST 528640            // 256 KB refine list (cap 65536)
#define W_LOSSP 790784            // 32 KB per-block loss partials (8192 f32)
// end = 823552

#define RCAP   65536
// fp16 hi + (lo*2048) split: worst-case pairwise dist error ~3e-4.
// 1e-3 = >3x margin.
#define MARGIN 1e-3f

typedef __attribute__((ext_vector_type(8))) _Float16 half8v;
typedef __attribute__((ext_vector_type(4))) float f32x4;

// ---------------------------------------------------------------------------
// K0: init NEA=0.99*ea, NCS=0.99*cs; e2=||e||^2 (fp64 accum); chunk-major
// fp16 hi/lo codebook hl (lo scaled x2048); transposed f32 codebook
// embT[d][code]; zero ctr.
// ---------------------------------------------------------------------------
__global__ __launch_bounds__(256) void k_init(
    const float* __restrict__ emb, const float* __restrict__ ea,
    const float* __restrict__ cs, float* __restrict__ out,
    float* __restrict__ e2, _Float16* __restrict__ hl,
    float* __restrict__ embT, int* __restrict__ ctr)
{
    int j = blockIdx.x * 256 + threadIdx.x;   // 0..65535
    out[O_NEA + j] = 0.99f * ea[j];

    // embT[d*1024+code] = emb[code*64+d]; j = code*64+d -> coalesced read
    {
        int code = j >> 6, d = j & 63;
        embT[d * KCB + code] = emb[j];
    }
    if (j < KCB) {
        out[O_NCS + j] = 0.99f * cs[j];
        const float* er = emb + j * DCV;
        double s = 0.0;
        #pragma unroll
        for (int d = 0; d < DCV; ++d) { double v = (double)er[d]; s += v * v; }
        e2[j] = (float)s;
    }
    if (j < 8192) {
        int code = j >> 3, q = j & 7;
        int ch = code >> 6, lc = code & 63;
        const float* src = emb + code * DCV + q * 8;
        half8v h, l;
        #pragma unroll
        for (int t = 0; t < 8; ++t) {
            float x = src[t];
            _Float16 hx = (_Float16)x;
            h[t] = hx;
            l[t] = (_Float16)((x - (float)hx) * 2048.0f);
        }
        *(half8v*)(hl + (size_t)(((ch * 2 + 0) * 8 + q) * 64 + lc) * 8) = h;
        *(half8v*)(hl + (size_t)(((ch * 2 + 1) * 8 + q) * 64 + lc) * 8) = l;
    }
    if (j == 0) { *ctr = 0; }
}

// ---------------------------------------------------------------------------
// K1: MFMA distance argmin, fp16 hi/lo, double-buffered async LDS staging.
// Block = 128 rows (4 waves x 32). 16 chunks of 64 codes staged via
// global_load_lds(16B). Per 16-code sub: 12 mfma_f32_16x16x32_f16 in 4
// independent chains. dist-x^2 = e2 - 2*(ah + ac/2048). Near-ties
// (gap < MARGIN) flagged for fp64 refine.
// ---------------------------------------------------------------------------
__global__ __launch_bounds__(256, 2) void k_dist(
    const float* __restrict__ ze, const char* __restrict__ hl,
    const float* __restrict__ e2g, float* __restrict__ out,
    int* __restrict__ ctr, int* __restrict__ rlist)
{
    __shared__ _Float16 lds[2][8192];     // 2 x 16 KB: [arr(2)][q(8)][code(64)][8]

    int tid  = threadIdx.x;
    int lane = tid & 63, w = tid >> 6;
    int g = lane >> 4, c = lane & 15;

    #define STAGE(buf, ch)                                                     \
        {                                                                      \
            _Pragma("unroll")                                                  \
            for (int r = 0; r < 4; ++r) {                                      \
                int off = (r * 4 + w) * 1024 + lane * 16;                      \
                __builtin_amdgcn_global_load_lds(                              \
                    (const __attribute__((address_space(1))) void*)            \
                        (hl + (size_t)(ch) * 16384 + off),                     \
                    (__attribute__((address_space(3))) void*)                  \
                        ((char*)lds[buf] + off),                               \
                    16, 0, 0);                                                 \
            }                                                                  \
        }

    // A-fragments: row = lane&15, k = kh*32 + 8*(lane>>4) + j (same bijection as B)
    int rowbase = blockIdx.x * 128 + w * 32;
    half8v ahi[2][2], alo[2][2];
    #pragma unroll
    for (int t = 0; t < 2; ++t) {
        int n = rowbase + t * 16 + c;
        const float* base = ze + (size_t)(n >> 12) * CHW + (n & 4095);
        #pragma unroll
        for (int kh = 0; kh < 2; ++kh) {
            #pragma unroll
            for (int j = 0; j < 8; ++j) {
                int k = kh * 32 + g * 8 + j;
                float x = base[(size_t)k * HWN];
                _Float16 hx = (_Float16)x;
                ahi[t][kh][j] = hx;
                alo[t][kh][j] = (_Float16)((x - (float)hx) * 2048.0f);
            }
        }
    }

    float best[8], second[8];
    int   bidx[8];
    #pragma unroll
    for (int i = 0; i < 8; ++i) { best[i] = 3.4e38f; second[i] = 3.4e38f; bidx[i] = 0; }

    STAGE(0, 0);
    __syncthreads();          // drains vmcnt -> buf0 ready

    int cur = 0;
    for (int ch = 0; ch < 16; ++ch) {
        if (ch < 15) STAGE(cur ^ 1, ch + 1);   // async prefetch next chunk

        const _Float16* L = lds[cur];
        #pragma unroll
        for (int sub = 0; sub < 4; ++sub) {
            int boff = (sub * 16 + c) * 8;
            half8v bh0 = *(const half8v*)&L[(g * 64) * 8 + boff];
            half8v bh1 = *(const half8v*)&L[((4 + g) * 64) * 8 + boff];
            half8v bl0 = *(const half8v*)&L[((8 + g) * 64) * 8 + boff];
            half8v bl1 = *(const half8v*)&L[((12 + g) * 64) * 8 + boff];

            f32x4 a0h = {0.f, 0.f, 0.f, 0.f}, a1h = {0.f, 0.f, 0.f, 0.f};
            f32x4 a0c = {0.f, 0.f, 0.f, 0.f}, a1c = {0.f, 0.f, 0.f, 0.f};
            a0h = __builtin_amdgcn_mfma_f32_16x16x32_f16(ahi[0][0], bh0, a0h, 0, 0, 0);
            a1h = __builtin_amdgcn_mfma_f32_16x16x32_f16(ahi[1][0], bh0, a1h, 0, 0, 0);
            a0h = __builtin_amdgcn_mfma_f32_16x16x32_f16(ahi[0][1], bh1, a0h, 0, 0, 0);
            a1h = __builtin_amdgcn_mfma_f32_16x16x32_f16(ahi[1][1], bh1, a1h, 0, 0, 0);
            a0c = __builtin_amdgcn_mfma_f32_16x16x32_f16(ahi[0][0], bl0, a0c, 0, 0, 0);
            a1c = __builtin_amdgcn_mfma_f32_16x16x32_f16(ahi[1][0], bl0, a1c, 0, 0, 0);
            a0c = __builtin_amdgcn_mfma_f32_16x16x32_f16(ahi[0][1], bl1, a0c, 0, 0, 0);
            a1c = __builtin_amdgcn_mfma_f32_16x16x32_f16(ahi[1][1], bl1, a1c, 0, 0, 0);
            a0c = __builtin_amdgcn_mfma_f32_16x16x32_f16(alo[0][0], bh0, a0c, 0, 0, 0);
            a1c = __builtin_amdgcn_mfma_f32_16x16x32_f16(alo[1][0], bh0, a1c, 0, 0, 0);
            a0c = __builtin_amdgcn_mfma_f32_16x16x32_f16(alo[0][1], bh1, a0c, 0, 0, 0);
            a1c = __builtin_amdgcn_mfma_f32_16x16x32_f16(alo[1][1], bh1, a1c, 0, 0, 0);

            float e2v = e2g[ch * 64 + sub * 16 + c];   // 4KB table, L1-resident
            int  code = ch * 64 + sub * 16 + c;
            #pragma unroll
            for (int t = 0; t < 2; ++t) {
                f32x4 avh = t ? a1h : a0h;
                f32x4 avc = t ? a1c : a0c;
                #pragma unroll
                for (int r = 0; r < 4; ++r) {
                    int i = t * 4 + r;
                    float dotv = fmaf(avc[r], 4.8828125e-4f, avh[r]);  // ah + ac/2048
                    float s = fmaf(-2.f, dotv, e2v);    // dist - x^2 (row-const drop)
                    bool lb = s < best[i];
                    second[i] = fminf(second[i], fmaxf(best[i], s));
                    best[i]   = fminf(best[i], s);
                    bidx[i]   = lb ? code : bidx[i];
                }
            }
        }
        __syncthreads();      // next buffer ready; current safe to overwrite
        cur ^= 1;
    }

    #pragma unroll
    for (int i = 0; i < 8; ++i) {
        float b = best[i], s2 = second[i];
        int bi = bidx[i];
        #pragma unroll
        for (int m = 1; m < 16; m <<= 1) {
            float ob = __shfl_xor(b, m, 64);
            float os = __shfl_xor(s2, m, 64);
            int   oi = __shfl_xor(bi, m, 64);
            float ns = fminf(fmaxf(b, ob), fminf(s2, os));
            bi = (ob < b || (ob == b && oi < bi)) ? oi : bi;
            b  = fminf(b, ob);
            s2 = ns;
        }
        if (c == 0) {
            int t = i >> 2, r = i & 3;
            int n = rowbase + t * 16 + g * 4 + r;
            out[O_IDX + n] = (float)bi;
            if (s2 - b < MARGIN) {
                int p = atomicAdd(ctr, 1);
                if (p < RCAP) rlist[p] = n;
            }
        }
    }
    #undef STAGE
}

// ---------------------------------------------------------------------------
// K2: fp64 exact argmin for flagged near-ties; fixes index only. One wave
// per candidate.
// ---------------------------------------------------------------------------
__global__ __launch_bounds__(256) void k_refine(
    const float* __restrict__ ze, const float* __restrict__ emb,
    float* __restrict__ out, const int* __restrict__ ctr,
    const int* __restrict__ rlist)
{
    int lane = threadIdx.x & 63;
    int gw   = (blockIdx.x * blockDim.x + threadIdx.x) >> 6;
    int nw   = (gridDim.x * blockDim.x) >> 6;
    int cnt  = *ctr;
    if (cnt > RCAP) cnt = RCAP;

    for (int i = gw; i < cnt; i += nw) {
        int n = rlist[i];
        const float* zp = ze + (size_t)(n >> 12) * CHW + (n & 4095);
        float x[DCV];
        #pragma unroll
        for (int d = 0; d < DCV; ++d) x[d] = zp[(size_t)d * HWN];  // uniform -> broadcast

        double bd = 1e300;
        int    bi = 0;
        #pragma unroll 1
        for (int cc = 0; cc < KCB / 64; ++cc) {
            int k = cc * 64 + lane;
            const float4* eb4 = (const float4*)(emb + k * DCV);
            double a0 = 0.0, a1 = 0.0;
            #pragma unroll
            for (int q = 0; q < DCV / 4; ++q) {
                float4 v = eb4[q];
                double d0 = (double)x[q * 4 + 0] - (double)v.x;
                double d1 = (double)x[q * 4 + 1] - (double)v.y;
                double d2 = (double)x[q * 4 + 2] - (double)v.z;
                double d3 = (double)x[q * 4 + 3] - (double)v.w;
                a0 = fma(d0, d0, a0); a1 = fma(d1, d1, a1);
                a0 = fma(d2, d2, a0); a1 = fma(d3, d3, a1);
            }
            double dist = a0 + a1;
            if (dist < bd || (dist == bd && k < bi)) { bd = dist; bi = k; }
        }
        #pragma unroll
        for (int off = 32; off > 0; off >>= 1) {
            double od = __shfl_xor(bd, off, 64);
            int    oi = __shfl_xor(bi, off, 64);
            if (od < bd || (od == bd && oi < bi)) { bd = od; bi = oi; }
        }
        if (lane == 0) out[O_IDX + n] = (float)bi;
    }
}

// ---------------------------------------------------------------------------
// K3a: z_q_st + commitment loss, pure streaming at full occupancy.
// Thread <-> (b, d, hw4): float4 read/write, embT row gather (L1, block-
// uniform d). Per-block loss partial -> plain store to lossp[block]
// (NO global atomic: 8192 same-address atomics serialized at ~12.7ns each
// = the entire 104us of r10's k_zq).
// ---------------------------------------------------------------------------
__global__ __launch_bounds__(256) void k_zq(
    const float* __restrict__ ze, const float* __restrict__ embT,
    float* __restrict__ out, float* __restrict__ lossp)
{
    int j  = blockIdx.x * 256 + threadIdx.x;  // 0..2M-1
    int b  = j >> 16;          // 32
    int d  = (j >> 10) & 63;   // 64
    int h4 = j & 1023;         // float4 unit over hw

    size_t off = (size_t)b * CHW + (size_t)d * HWN + h4 * 4;
    float4 zv = *(const float4*)(ze + off);
    float4 iv = *(const float4*)(out + O_IDX + b * HWN + h4 * 4);
    const float* eT = embT + d * KCB;
    float e0 = eT[(int)iv.x], e1 = eT[(int)iv.y];
    float e2 = eT[(int)iv.z], e3 = eT[(int)iv.w];

    float4 q;
    q.x = zv.x + (e0 - zv.x);   // straight-through f32 rounding
    q.y = zv.y + (e1 - zv.y);
    q.z = zv.z + (e2 - zv.z);
    q.w = zv.w + (e3 - zv.w);
    *(float4*)(out + O_ZQ + off) = q;

    float d0 = zv.x - e0, d1 = zv.y - e1, d2 = zv.z - e2, d3 = zv.w - e3;
    float lp = fmaf(d0, d0, fmaf(d1, d1, fmaf(d2, d2, d3 * d3)));

    #pragma unroll
    for (int o = 32; o > 0; o >>= 1) lp += __shfl_down(lp, o, 64);
    __shared__ float wsum[4];
    int lane = threadIdx.x & 63, wid = threadIdx.x >> 6;
    if (lane == 0) wsum[wid] = lp;
    __syncthreads();
    if (threadIdx.x == 0)
        lossp[blockIdx.x] = (wsum[0] + wsum[1]) + (wsum[2] + wsum[3]);
}

// ---------------------------------------------------------------------------
// K3b: dw segment-sum + counts. Block = (dim d, chunk of 4 batches):
// 512 blocks, LDS 8 KB. All global reads coalesced; ds_atomic bank =
// idx%32 (~2-way). d==0 blocks also bin counts. Flush: 0.01*bins into NEA.
// ---------------------------------------------------------------------------
__global__ __launch_bounds__(256) void k_dw(
    const float* __restrict__ ze, const float* __restrict__ outIdx,
    float* __restrict__ out)
{
    int d = blockIdx.x & 63, chunk = blockIdx.x >> 6;   // 8 chunks x 4 batches
    __shared__ float bins[KCB];
    __shared__ float cnt[KCB];
    for (int i = threadIdx.x; i < KCB; i += 256) { bins[i] = 0.f; cnt[i] = 0.f; }
    __syncthreads();

    #pragma unroll
    for (int bb = 0; bb < 4; ++bb) {
        int b = chunk * 4 + bb;
        const float* zp = ze + (size_t)b * CHW + (size_t)d * HWN;
        const float* ip = outIdx + b * HWN;
        for (int t = threadIdx.x; t < HWN; t += 256) {
            int idx = (int)ip[t];
            atomicAdd(&bins[idx], zp[t]);
            if (d == 0) atomicAdd(&cnt[idx], 1.f);
        }
    }
    __syncthreads();

    for (int k = threadIdx.x; k < KCB; k += 256) {
        float v = bins[k];
        if (v != 0.f) atomicAdd(&out[O_NEA + k * DCV + d], 0.01f * v);
        if (d == 0) {
            float cv = cnt[k];
            if (cv != 0.f) atomicAdd(&out[O_NCS + k], 0.01f * cv);
        }
    }
}

// ---------------------------------------------------------------------------
// K4: fused stats+embed: each block redundantly reduces NCS (4 KB) to n,
// then computes its 256 NE outputs. Block 0 also reduces the 8192 loss
// partials (fp64) and writes the loss scalar.
// ---------------------------------------------------------------------------
__global__ __launch_bounds__(256) void k_fin(
    float* __restrict__ out, const float* __restrict__ lossp)
{
    __shared__ float red[4];
    int t = threadIdx.x;
    float s = 0.f;
    #pragma unroll
    for (int q = 0; q < 4; ++q) s += out[O_NCS + t * 4 + q];
    #pragma unroll
    for (int off = 32; off > 0; off >>= 1) s += __shfl_down(s, off, 64);
    int lane = t & 63, wid = t >> 6;
    if (lane == 0) red[wid] = s;
    __syncthreads();
    float n = red[0] + red[1] + red[2] + red[3];

    int j = blockIdx.x * 256 + t;      // 0..65535
    int k = j >> 6;
    float ncs = out[O_NCS + k];
    float sm = (ncs + 1e-5f) / (n + (float)KCB * 1e-5f) * n;
    out[O_NE + j] = out[O_NEA + j] / sm;

    if (blockIdx.x == 0) {
        double ls = 0.0;
        for (int i = t; i < 8192; i += 256) ls += (double)lossp[i];
        #pragma unroll
        for (int off = 32; off > 0; off >>= 1) ls += __shfl_down(ls, off, 64);
        __shared__ double redl[4];
        if (lane == 0) redl[wid] = ls;
        __syncthreads();
        if (t == 0) {
            double tot = (redl[0] + redl[1]) + (redl[2] + redl[3]);
            out[O_LOSS] = (float)(0.25 * tot / (double)(NTOT * DCV));
        }
    }
}

// ---------------------------------------------------------------------------
extern "C" void kernel_launch(void* const* d_in, const int* in_sizes, int n_in,
                              void* d_out, int out_size, void* d_ws, size_t ws_size,
                              hipStream_t stream)
{
    const float* ze  = (const float*)d_in[0];
    const float* emb = (const float*)d_in[1];
    const float* cs  = (const float*)d_in[2];
    const float* ea  = (const float*)d_in[3];
    float* out = (float*)d_out;

    char*     w     = (char*)d_ws;
    int*      ctr   = (int*)(w + W_CTR);
    float*    e2    = (float*)(w + W_E2);
    _Float16* hl    = (_Float16*)(w + W_HLT);
    float*    embT  = (float*)(w + W_EMBT);
    int*      rlist = (int*)(w + W_RLIST);
    float*    lossp = (float*)(w + W_LOSSP);

    k_init  <<<256, 256, 0, stream>>>(emb, ea, cs, out, e2, hl, embT, ctr);
    k_dist  <<<1024, 256, 0, stream>>>(ze, (const char*)hl, e2, out, ctr, rlist);
    k_refine<<<256, 256, 0, stream>>>(ze, emb, out, ctr, rlist);
    k_zq    <<<8192, 256, 0, stream>>>(ze, embT, out, lossp);
    k_dw    <<<512, 256, 0, stream>>>(ze, (const float*)(out + O_IDX), out);
    k_fin   <<<256, 256, 0, stream>>>(out, lossp);
}